// Round 3
// baseline (17.323 us; speedup 1.0000x reference)
//
#include <hip/hip_runtime.h>
#include <math.h>

// MBR (min bounding rectangle) area via brute-force hull-edge enumeration.
// One thread per sample (K=8 points). For each ordered pair (i,j), i!=j:
//   edge iff for all l not in {i,j}: cross(p_j-p_i, p_l-p_i) >= 0
// (l==i and l==j give exactly-0 crosses in the reference's separate-rounding
//  arithmetic, so they always pass; we skip them at compile time because FMA
//  contraction would otherwise turn the exact 0 into a tiny signed residue.)
// Reference folds edge angle t=atan2(dy,dx) as ang=|fmod(t,pi/2)| and rotates
// by [[cos,sin],[-sin,cos]]. Identity (verified over all 4 quadrants):
//   (cos(ang),sin(ang)) = (|dx|,|dy|)/L if dx>=0 else (|dy|,|dx|)/L.
// We use unnormalized (a,b)=(L*cos, L*sin) and divide the area by L^2 once.

// Separate-rounding cross product: match numpy's sign decisions on
// near-collinear triples (FMA contraction would produce a rounding residue
// where the reference gets an exact cancellation).
__device__ __forceinline__ float cross_sep(float ax, float ay, float bx, float by) {
#pragma clang fp contract(off)
    return ax * by - ay * bx;
}

__global__ __launch_bounds__(256)
void mbr_area_kernel(const float* __restrict__ corners,
                     float* __restrict__ out, int n) {
    int t = blockIdx.x * blockDim.x + threadIdx.x;
    if (t >= n) return;

    // Load 8 points (16 floats) as 4x float4.
    const float4* p4 = (const float4*)(corners + (size_t)t * 16);
    float px[8], py[8];
#pragma unroll
    for (int q = 0; q < 4; ++q) {
        float4 v = p4[q];
        px[2 * q + 0] = v.x; py[2 * q + 0] = v.y;
        px[2 * q + 1] = v.z; py[2 * q + 1] = v.w;
    }

    float best = INFINITY;
#pragma unroll
    for (int i = 0; i < 8; ++i) {
        // Points relative to p_i (reused across all j for the cross tests).
        float qx[8], qy[8];
#pragma unroll
        for (int l = 0; l < 8; ++l) {
            qx[l] = px[l] - px[i];
            qy[l] = py[l] - py[i];
        }
#pragma unroll
        for (int j = 0; j < 8; ++j) {
            if (j == i) continue;  // compile-time skip (both loops unrolled)
            float dx = qx[j], dy = qy[j];

            // Hull-edge test: all other points left of (or on) line i->j.
            bool edge = true;
#pragma unroll
            for (int l = 0; l < 8; ++l) {
                if (l == i || l == j) continue;  // exact-0 crosses: always pass
                edge = edge && (cross_sep(dx, dy, qx[l], qy[l]) >= 0.0f);
            }

            // Unnormalized rotation coefficients (see header comment).
            float adx = fabsf(dx), ady = fabsf(dy);
            float a = (dx >= 0.0f) ? adx : ady;
            float b = (dx >= 0.0f) ? ady : adx;

            float umin =  3.0e38f, umax = -3.0e38f;
            float vmin =  3.0e38f, vmax = -3.0e38f;
#pragma unroll
            for (int l = 0; l < 8; ++l) {
                float u = a * px[l] + b * py[l];   //  cos*x + sin*y  (scaled L)
                float v = a * py[l] - b * px[l];   // -sin*x + cos*y  (scaled L)
                umin = fminf(umin, u); umax = fmaxf(umax, u);
                vmin = fminf(vmin, v); vmax = fmaxf(vmax, v);
            }
            float inv = __builtin_amdgcn_rcpf(dx * dx + dy * dy);
            float area = (umax - umin) * (vmax - vmin) * inv;
            best = edge ? fminf(best, area) : best;
        }
    }
    out[t] = best;
}

extern "C" void kernel_launch(void* const* d_in, const int* in_sizes, int n_in,
                              void* d_out, int out_size, void* d_ws, size_t ws_size,
                              hipStream_t stream) {
    const float* corners = (const float*)d_in[0];
    float* out = (float*)d_out;
    int n = in_sizes[0] / 16;  // K*2 = 16 floats per sample
    int threads = 256;
    int blocks = (n + threads - 1) / threads;
    mbr_area_kernel<<<blocks, threads, 0, stream>>>(corners, out, n);
}

// Round 4
// 13.551 us; speedup vs baseline: 1.2784x; 1.2784x over previous
//
#include <hip/hip_runtime.h>
#include <math.h>

// MBR area, 8 lanes per sample. Lane k owns pivot i=k: tests the 7 ordered
// pairs (k, j), j!=k, for CCW-hull-edge-ness and computes the candidate box
// area for each edge. 3-step shfl_xor min-reduce across the 8-lane group.
//
// Trick: lane k loads the points ROTATED (slot l <- original point (l+k)&7),
// so its pivot is always slot 0 and every register index is compile-time
// (runtime-indexed register arrays go to scratch — rule #20).
//
// Edge test matches the reference's separate-rounding cross products; the
// exactly-zero l==i / l==j crosses are skipped at compile time. Rotation
// identity: reference's (cos,sin) after fmod-pi/2 folding equals
// (|dx|,|dy|)/L for dx>=0 else (|dy|,|dx|)/L — we use unnormalized (a,b)
// and divide the area by L^2 = dx^2+dy^2 once.

__device__ __forceinline__ float cross_sep(float ax, float ay, float bx, float by) {
#pragma clang fp contract(off)
    return ax * by - ay * bx;
}

__global__ __launch_bounds__(256)
void mbr_area_kernel(const float* __restrict__ corners,
                     float* __restrict__ out, int n) {
    int t = blockIdx.x * blockDim.x + threadIdx.x;
    int s = t >> 3;   // sample
    int k = t & 7;    // pivot owned by this lane
    if (s >= n) return;

    // Rotated load: slot l holds original point (l+k)&7. 8B loads, L1-served
    // (8 lanes share each sample's 64B).
    const float2* pts = (const float2*)(corners + (size_t)s * 16);
    float px[8], py[8];
#pragma unroll
    for (int l = 0; l < 8; ++l) {
        float2 v = pts[(l + k) & 7];
        px[l] = v.x; py[l] = v.y;
    }

    // Deltas relative to the pivot (slot 0).
    float qx[8], qy[8];
#pragma unroll
    for (int l = 1; l < 8; ++l) {
        qx[l] = px[l] - px[0];
        qy[l] = py[l] - py[0];
    }

    float best = INFINITY;
#pragma unroll
    for (int j = 1; j < 8; ++j) {
        float dx = qx[j], dy = qy[j];

        // Hull-edge test: all other points left of (or on) line pivot->j.
        bool edge = true;
#pragma unroll
        for (int l = 1; l < 8; ++l) {
            if (l == j) continue;
            edge = edge && (cross_sep(dx, dy, qx[l], qy[l]) >= 0.0f);
        }

        // Unnormalized rotation coefficients.
        float adx = fabsf(dx), ady = fabsf(dy);
        float a = (dx >= 0.0f) ? adx : ady;
        float b = (dx >= 0.0f) ? ady : adx;

        float umin =  3.0e38f, umax = -3.0e38f;
        float vmin =  3.0e38f, vmax = -3.0e38f;
#pragma unroll
        for (int l = 0; l < 8; ++l) {
            float u = a * px[l] + b * py[l];   //  cos*x + sin*y  (scaled L)
            float v = a * py[l] - b * px[l];   // -sin*x + cos*y  (scaled L)
            umin = fminf(umin, u); umax = fmaxf(umax, u);
            vmin = fminf(vmin, v); vmax = fmaxf(vmax, v);
        }
        float inv = __builtin_amdgcn_rcpf(dx * dx + dy * dy);
        float area = (umax - umin) * (vmax - vmin) * inv;
        best = edge ? fminf(best, area) : best;
    }

    // Min-reduce across the 8-lane group (aligned within the wave).
    best = fminf(best, __shfl_xor(best, 1));
    best = fminf(best, __shfl_xor(best, 2));
    best = fminf(best, __shfl_xor(best, 4));
    if (k == 0) out[s] = best;
}

extern "C" void kernel_launch(void* const* d_in, const int* in_sizes, int n_in,
                              void* d_out, int out_size, void* d_ws, size_t ws_size,
                              hipStream_t stream) {
    const float* corners = (const float*)d_in[0];
    float* out = (float*)d_out;
    int n = in_sizes[0] / 16;   // K*2 = 16 floats per sample
    int threads = 256;
    long long total = (long long)n * 8;
    int blocks = (int)((total + threads - 1) / threads);
    mbr_area_kernel<<<blocks, threads, 0, stream>>>(corners, out, n);
}

// Round 5
// 11.133 us; speedup vs baseline: 1.5560x; 1.2171x over previous
//
#include <hip/hip_runtime.h>
#include <math.h>

// MBR area via hull-edge compaction. 8 lanes per sample.
// Phase 1: lane k (pivot = original point k, loaded into slot 0 via rotated
//   load: slot l <- point (l+k)&7) computes 7 edge booleans from the 21
//   unique crosses c[j][l] (j<l). cross for the mirrored pair is the EXACT
//   IEEE negation, so edge_j tests c[j][l]>=0 (j<l) and c[l][j]<=0 (j>l),
//   matching the reference's separate-rounding sign decisions bit-exactly.
//   (l==pivot and l==j crosses are exactly 0 in the reference -> always pass.)
// Phase 2: 7 ballots broadcast the group's 56 edge bits; lane m selects the
//   m-th set edge, reloads its endpoints (identical rounding), and does ONE
//   rotate/min-max block. min/max over the rotated-order point set is
//   order-invariant. A base+=8 loop (ballot-break) covers the ~impossible
//   >8-edge exact-collinear case.
// Rotation identity: reference's (cos,sin) after fmod-pi/2 folding equals
//   (|dx|,|dy|)/L if dx>=0 else (|dy|,|dx|)/L; we use unnormalized (a,b) and
//   divide by L^2 once (rcp within tolerance: absmax 0.0625 vs 0.655).

__device__ __forceinline__ float cross_sep(float ax, float ay, float bx, float by) {
#pragma clang fp contract(off)
    return ax * by - ay * bx;
}

__global__ __launch_bounds__(256)
void mbr_area_kernel(const float* __restrict__ corners,
                     float* __restrict__ out, int n) {
    int t = blockIdx.x * blockDim.x + threadIdx.x;
    int s = t >> 3;   // sample
    int k = t & 7;    // this lane's pivot (original index)
    if (s >= n) return;

    // Rotated load: slot l holds original point (l+k)&7 (pivot in slot 0).
    const float2* pts = (const float2*)(corners + (size_t)s * 16);
    float px[8], py[8];
#pragma unroll
    for (int l = 0; l < 8; ++l) {
        float2 v = pts[(l + k) & 7];
        px[l] = v.x; py[l] = v.y;
    }

    // Deltas relative to the pivot.
    float qx[8], qy[8];
#pragma unroll
    for (int l = 1; l < 8; ++l) {
        qx[l] = px[l] - px[0];
        qy[l] = py[l] - py[0];
    }

    // Phase 1: edge bits from 21 unique crosses.
    bool edge[8];
#pragma unroll
    for (int j = 1; j < 8; ++j) edge[j] = true;
#pragma unroll
    for (int j = 1; j < 8; ++j) {
#pragma unroll
        for (int l = j + 1; l < 8; ++l) {
            float c = cross_sep(qx[j], qy[j], qx[l], qy[l]);
            edge[j] = edge[j] && (c >= 0.0f);   // test point l for edge (0->j)
            edge[l] = edge[l] && (c <= 0.0f);   // exact negation for (0->l)
        }
    }

    // Broadcast: bit k of bytes[j] = edge (orig k -> orig (k+j)&7).
    int lane = threadIdx.x & 63;
    int gsh = lane & 56;            // 8 * (group index within wave)
    unsigned bytes[8];
#pragma unroll
    for (int j = 1; j < 8; ++j) {
        unsigned long long bal = __ballot(edge[j]);
        bytes[j] = (unsigned)((bal >> gsh) & 0xFFull);
    }
    int total = 0;
#pragma unroll
    for (int j = 1; j < 8; ++j) total += __popc(bytes[j]);

    // Phase 2: lane m processes the (base+m)-th edge of its group.
    float best = INFINITY;
    for (int base = 0; base < 56; base += 8) {
        if (__ballot(base < total) == 0) break;   // normally breaks at base=8
        int m = base + k;
        if (m < total) {
            // Select m-th set bit across bytes[1..7] (t-major, bit-minor).
            int ft = 0, fm = 0; unsigned fbyte = 0; int mm = m;
#pragma unroll
            for (int tt = 1; tt < 8; ++tt) {
                int c = __popc(bytes[tt]);
                if (ft == 0 && mm < c) { ft = tt; fbyte = bytes[tt]; fm = mm; }
                if (ft == 0) mm -= c;
            }
#pragma unroll
            for (int r = 0; r < 7; ++r)       // clear fm lowest set bits
                if (r < fm) fbyte &= (fbyte - 1);
            int i = __ffs(fbyte) - 1;         // edge pivot (original index)
            int j = (i + ft) & 7;             // edge endpoint (original index)

            // Reload endpoints (L1-hot): identical values -> identical dx,dy.
            float2 Pi = pts[i], Pj = pts[j];
            float dx = Pj.x - Pi.x, dy = Pj.y - Pi.y;

            float adx = fabsf(dx), ady = fabsf(dy);
            float a = (dx >= 0.0f) ? adx : ady;
            float b = (dx >= 0.0f) ? ady : adx;

            float umin =  3.0e38f, umax = -3.0e38f;
            float vmin =  3.0e38f, vmax = -3.0e38f;
#pragma unroll
            for (int l = 0; l < 8; ++l) {
                float u = a * px[l] + b * py[l];
                float v = a * py[l] - b * px[l];
                umin = fminf(umin, u); umax = fmaxf(umax, u);
                vmin = fminf(vmin, v); vmax = fmaxf(vmax, v);
            }
            float inv = __builtin_amdgcn_rcpf(dx * dx + dy * dy);
            best = fminf(best, (umax - umin) * (vmax - vmin) * inv);
        }
    }

    // Min-reduce across the 8-lane group.
    best = fminf(best, __shfl_xor(best, 1));
    best = fminf(best, __shfl_xor(best, 2));
    best = fminf(best, __shfl_xor(best, 4));
    if (k == 0) out[s] = best;
}

extern "C" void kernel_launch(void* const* d_in, const int* in_sizes, int n_in,
                              void* d_out, int out_size, void* d_ws, size_t ws_size,
                              hipStream_t stream) {
    const float* corners = (const float*)d_in[0];
    float* out = (float*)d_out;
    int n = in_sizes[0] / 16;   // K*2 = 16 floats per sample
    int threads = 256;
    long long total = (long long)n * 8;
    int blocks = (int)((total + threads - 1) / threads);
    mbr_area_kernel<<<blocks, threads, 0, stream>>>(corners, out, n);
}

// Round 6
// 9.752 us; speedup vs baseline: 1.7764x; 1.1417x over previous
//
#include <hip/hip_runtime.h>
#include <math.h>

// MBR area, 8 lanes/sample, no cross-lane edge redistribution.
// Geometry: for a CCW convex hull, each pivot i has AT MOST ONE outgoing hull
// edge (i,j) ("all other points left-of-or-on line i->j"); >1 only when
// boundary points are exactly collinear, in which case all passing j share a
// direction -> identical box area (mod rounding << 0.655 tolerance). So lane
// k = pivot k finds its own first passing j and rotates in-place. No ballots.
//
// Rotated load: slot l <- original point (l+k)&7, so the pivot is slot 0 and
// all register indexing is compile-time (rule #20). qx/qy equal the
// reference's apex-k delta values bit-exactly; min/max over the rotated point
// order is order-invariant.
//
// Edge test: 21 unique crosses, separate rounding (contract off) to match
// numpy's sign decisions; mirrored pair uses the EXACT IEEE negation (free
// input modifier) with float-min accumulation: edge_j <=> min over l of
// (+-c) >= 0. l==pivot / l==j crosses are exactly 0 in the reference ->
// always pass -> skipped at compile time.
//
// Rotation identity: reference's (cos,sin) after |fmod(atan2, pi/2)| folding
// equals (|dx|,|dy|)/L if dx>=0 else (|dy|,|dx|)/L. We use unnormalized
// (a,b) = L*(cos,sin) and divide the area by L^2 = dx^2+dy^2 once (rcp ok:
// absmax 0.0625 vs threshold 0.655).

__device__ __forceinline__ float cross_sep(float ax, float ay, float bx, float by) {
#pragma clang fp contract(off)
    return ax * by - ay * bx;
}

__global__ __launch_bounds__(256)
void mbr_area_kernel(const float* __restrict__ corners,
                     float* __restrict__ out, int n) {
    int t = blockIdx.x * blockDim.x + threadIdx.x;
    int s = t >> 3;   // sample
    int k = t & 7;    // this lane's pivot (original index)
    if (s >= n) return;

    // Rotated load: slot l holds original point (l+k)&7 (pivot in slot 0).
    const float2* pts = (const float2*)(corners + (size_t)s * 16);
    float px[8], py[8];
#pragma unroll
    for (int l = 0; l < 8; ++l) {
        float2 v = pts[(l + k) & 7];
        px[l] = v.x; py[l] = v.y;
    }

    // Deltas relative to the pivot.
    float qx[8], qy[8];
#pragma unroll
    for (int l = 1; l < 8; ++l) {
        qx[l] = px[l] - px[0];
        qy[l] = py[l] - py[0];
    }

    // Phase 1: acc[j] = min over l of sign-adjusted cross; edge_j <=> acc[j]>=0.
    float acc[8];
#pragma unroll
    for (int j = 1; j < 8; ++j) acc[j] = INFINITY;
#pragma unroll
    for (int j = 1; j < 8; ++j) {
#pragma unroll
        for (int l = j + 1; l < 8; ++l) {
            float c = cross_sep(qx[j], qy[j], qx[l], qy[l]);
            acc[j] = fminf(acc[j],  c);   // test point l for edge (0->j)
            acc[l] = fminf(acc[l], -c);   // exact negation for edge (0->l)
        }
    }

    // First passing j (unique in general position; collinear dups share the
    // direction -> same area).
    float bdx = 0.0f, bdy = 0.0f;
    bool found = false;
#pragma unroll
    for (int j = 1; j < 8; ++j) {
        bool e = acc[j] >= 0.0f;
        bool take = e && !found;
        bdx = take ? qx[j] : bdx;
        bdy = take ? qy[j] : bdy;
        found = found || e;
    }

    // Phase 2: one rotate/min-max block for this lane's edge (if any).
    float a0 = fabsf(bdx), b0 = fabsf(bdy);
    float a = (bdx >= 0.0f) ? a0 : b0;
    float b = (bdx >= 0.0f) ? b0 : a0;

    float umin =  3.0e38f, umax = -3.0e38f;
    float vmin =  3.0e38f, vmax = -3.0e38f;
#pragma unroll
    for (int l = 0; l < 8; ++l) {
        float u = a * px[l] + b * py[l];   //  cos*x + sin*y  (scaled L)
        float v = a * py[l] - b * px[l];   // -sin*x + cos*y  (scaled L)
        umin = fminf(umin, u); umax = fmaxf(umax, u);
        vmin = fminf(vmin, v); vmax = fmaxf(vmax, v);
    }
    float inv = __builtin_amdgcn_rcpf(bdx * bdx + bdy * bdy);
    float area = (umax - umin) * (vmax - vmin) * inv;
    float best = found ? area : INFINITY;

    // Min-reduce across the 8-lane group (aligned within the wave).
    best = fminf(best, __shfl_xor(best, 1));
    best = fminf(best, __shfl_xor(best, 2));
    best = fminf(best, __shfl_xor(best, 4));
    if (k == 0) out[s] = best;
}

extern "C" void kernel_launch(void* const* d_in, const int* in_sizes, int n_in,
                              void* d_out, int out_size, void* d_ws, size_t ws_size,
                              hipStream_t stream) {
    const float* corners = (const float*)d_in[0];
    float* out = (float*)d_out;
    int n = in_sizes[0] / 16;   // K*2 = 16 floats per sample
    int threads = 256;
    long long total = (long long)n * 8;
    int blocks = (int)((total + threads - 1) / threads);
    mbr_area_kernel<<<blocks, threads, 0, stream>>>(corners, out, n);
}